// Round 1
// baseline (184.459 us; speedup 1.0000x reference)
//
#include <hip/hip_runtime.h>
#include <math.h>

// Sizes (fixed by the problem)
#define BATCH 512   // scan sequence length (original batch dim)
#define E     128
#define DI    256
#define S     256
#define DTR   8
#define KCONV 4
#define JWX   520   // dt(8) + B(256) + C(256)

__device__ __forceinline__ float silu_f(float v) {
    return v / (1.0f + __expf(-v));
}

// ---------------------------------------------------------------------------
// kA: blocks 0..511  : conv2d+lin row-31 projection -> u31 (LDS) -> fused
//                      W_in projection -> xm, zg  (k2a absorbed here: the
//                      xz row is b-local, so no extra kernel/global trip)
//     blocks 512..522: W_x / W_out transposes (W_inT/W_dtT/c1wT no longer
//                      needed: W_in read row-wise here, c1w/W_dt read
//                      directly with coalesced float4 patterns in k2b)
// ---------------------------------------------------------------------------
__global__ __launch_bounds__(256) void kA_pre(
    const float* __restrict__ x, const float* __restrict__ conv_w,
    const float* __restrict__ conv_b, const float* __restrict__ lin_w,
    const float* __restrict__ lin_b, const float* __restrict__ W_in,
    const float* __restrict__ W_x, const float* __restrict__ W_out,
    float* __restrict__ xm, float* __restrict__ zg,
    float* __restrict__ W_xT, float* __restrict__ W_outT)
{
    const int tid = threadIdx.x;
    if (blockIdx.x >= 512) {
        // ---- transpose part ----
        const int bid = blockIdx.x - 512;
        const float* src; float* dst; int J, K, j0;
        if (bid < 9) { src = W_x;   dst = W_xT;   J = JWX; K = DI; j0 = bid * 64; }
        else         { src = W_out; dst = W_outT; J = E;   K = DI; j0 = (bid - 9) * 64; }
        const int j = j0 + (tid & 63);
        if (j >= J) return;
        for (int c = tid >> 6; c < K; c += 4)
            dst[c * J + j] = src[j * K + c];
        return;
    }

    // ---- conv2d + lin row 31 part ----
    const int b = blockIdx.x;
    __shared__ float lw[1024];
    __shared__ float red[10][4];
    __shared__ float Tsh[10];
    __shared__ float u[E];

    const float4 lv = ((const float4*)(lin_w + 31 * 1024))[tid];
    ((float4*)lw)[tid] = lv;
    __syncthreads();

    float acc[10];
#pragma unroll
    for (int k = 0; k < 10; k++) acc[k] = 0.0f;

    const float4 xv = ((const float4*)(x + (size_t)b * 1024))[tid];
    const int p0 = tid * 4;
    const int h = p0 >> 5, w0 = p0 & 31;
    const float xa[4] = {xv.x, xv.y, xv.z, xv.w};
#pragma unroll
    for (int k = 0; k < 4; k++) {
        const float xval = xa[k];
        const int w = w0 + k;
#pragma unroll
        for (int i = 0; i < 3; i++) {
            const int hh = h - (i - 1);
            if (hh < 0 || hh > 31) continue;
#pragma unroll
            for (int j = 0; j < 3; j++) {
                const int ww = w - (j - 1);
                if (ww < 0 || ww > 31) continue;
                acc[i * 3 + j] += xval * lw[hh * 32 + ww];
            }
        }
    }
    acc[9] = lv.x + lv.y + lv.z + lv.w;   // partial sum of lin_w row (SL)

    const int wv = tid >> 6, ln = tid & 63;
#pragma unroll
    for (int k = 0; k < 10; k++) {
#pragma unroll
        for (int m = 1; m < 64; m <<= 1) acc[k] += __shfl_xor(acc[k], m, 64);
    }
    if (ln == 0) {
#pragma unroll
        for (int k = 0; k < 10; k++) red[k][wv] = acc[k];
    }
    __syncthreads();
    if (tid < 10) Tsh[tid] = red[tid][0] + red[tid][1] + red[tid][2] + red[tid][3];
    __syncthreads();

    if (tid < E) {
        const int e = tid;
        float v = lin_b[31] + conv_b[e] * Tsh[9];
#pragma unroll
        for (int k = 0; k < 9; k++) v += conv_w[e * 9 + k] * Tsh[k];
        u[e] = v;
    }
    __syncthreads();

    // ---- fused k2a: xz[b,j] = sum_e u[e]*W_in[j,e]; j=tid -> xm, j=tid+256 -> zg
    // Per-wave working set of W_in rows = 64 rows x 512 B = 32 KB (L1-resident);
    // each W_in line fetched once per block from L2.
    {
        const float4* w0p = (const float4*)(W_in + (size_t)tid * E);
        const float4* w1p = (const float4*)(W_in + (size_t)(tid + 256) * E);
        float a0 = 0.0f;
#pragma unroll 8
        for (int e4 = 0; e4 < E / 4; e4++) {
            const float4 w = w0p[e4];
            a0 += u[4*e4]*w.x + u[4*e4+1]*w.y + u[4*e4+2]*w.z + u[4*e4+3]*w.w;
        }
        float a1 = 0.0f;
#pragma unroll 8
        for (int e4 = 0; e4 < E / 4; e4++) {
            const float4 w = w1p[e4];
            a1 += u[4*e4]*w.x + u[4*e4+1]*w.y + u[4*e4+2]*w.z + u[4*e4+3]*w.w;
        }
        xm[b * DI + tid] = a0;
        zg[b * DI + tid] = a1;
    }
}

// ---------------------------------------------------------------------------
// K2b: causal depthwise conv1d(K=4)+silu -> xs; dbl = xs @ W_x.T (via W_xT);
//      delta = softplus(dbl[:, :8] @ W_dt.T + b_dt); Bm/Cm split.
// Tile 4b x 64j, grid (128, 9). jgroup 0 also does xs_g write + delta.
// c1w read directly as float4 (c1w[c][0][0..3] contiguous); W_dt row (32 B)
// read directly -> contiguous per-wave access, no transposes needed.
// ---------------------------------------------------------------------------
__global__ __launch_bounds__(256) void k2b_conv_wx(
    const float* __restrict__ xm, const float* __restrict__ c1w,
    const float* __restrict__ conv1d_b, const float* __restrict__ W_xT,
    const float* __restrict__ W_dt, const float* __restrict__ b_dt,
    float* __restrict__ xs_g, float* __restrict__ delta_g,
    float* __restrict__ Bm, float* __restrict__ Cm)
{
    const int bb = blockIdx.x * 4;
    const int g = blockIdx.y;
    const int tid = threadIdx.x;
    __shared__ float xs[4][DI];
    __shared__ float dtin[4][8];

    // phase A: xs = silu(causal_conv1d(xm) + bias); coalesced
    for (int idx = tid; idx < 4 * DI; idx += 256) {
        const int r = idx >> 8, c = idx & 255;
        const int b = bb + r;
        const float4 wc = ((const float4*)c1w)[c];   // taps k=0..3
        float a = conv1d_b[c];
        if (b >= 3) a += xm[(b - 3) * DI + c] * wc.x;
        if (b >= 2) a += xm[(b - 2) * DI + c] * wc.y;
        if (b >= 1) a += xm[(b - 1) * DI + c] * wc.z;
        a += xm[b * DI + c] * wc.w;
        const float s = silu_f(a);
        xs[r][c] = s;
        if (g == 0) xs_g[b * DI + c] = s;
    }
    __syncthreads();

    // phase B: 1 output/thread; wave-uniform xs broadcast, coalesced W_xT
    const int r = tid >> 6;
    const int j = g * 64 + (tid & 63);
    if (j < JWX) {
        float a = 0.0f;
#pragma unroll 8
        for (int c = 0; c < DI; c++) a += xs[r][c] * W_xT[c * JWX + j];
        const int b = bb + r;
        if (j < DTR)          dtin[r][j] = a;
        else if (j < DTR + S) Bm[b * S + (j - DTR)] = a;
        else                  Cm[b * S + (j - DTR - S)] = a;
    }
    __syncthreads();

    // phase C: delta = softplus(dtin @ W_dt.T + b_dt) (jgroup 0 only)
    if (g == 0) {
        const int d = tid;
        const float bd = b_dt[d];
        const float4 wd0 = ((const float4*)(W_dt + d * DTR))[0];
        const float4 wd1 = ((const float4*)(W_dt + d * DTR))[1];
#pragma unroll
        for (int r2 = 0; r2 < 4; r2++) {
            float a = bd
                + dtin[r2][0]*wd0.x + dtin[r2][1]*wd0.y + dtin[r2][2]*wd0.z + dtin[r2][3]*wd0.w
                + dtin[r2][4]*wd1.x + dtin[r2][5]*wd1.y + dtin[r2][6]*wd1.z + dtin[r2][7]*wd1.w;
            const float sp = (a > 20.0f) ? a : log1pf(__expf(a));
            delta_g[(bb + r2) * DI + d] = sp;
        }
    }
}

// ---------------------------------------------------------------------------
// K3 chunked scan, up/down-sweep form (replaces local-scan + fixup):
//   k3u: per-chunk UP-SWEEP: h-recurrence only -> hloc, Dchunk.
//        No C loads, no cross-lane reductions, no y traffic.
//   k3d: per-chunk DOWN-SWEEP: compose carry h_in via the same Horner pass
//        k3c used (bit-compatible), then run the full recurrence from h_in,
//        producing y with a single plain store (no RMW, no second exp pass
//        over exp(cd*A)).
// ---------------------------------------------------------------------------
template <int NCv>
__global__ __launch_bounds__(256) void k3u_up(
    const float* __restrict__ A_log, const float* __restrict__ delta,
    const float* __restrict__ xs, const float* __restrict__ Bm,
    float* __restrict__ hloc, float* __restrict__ Dchunk)
{
    constexpr int TCv = BATCH / NCv;
    const int tid = threadIdx.x;
    const int wv = tid >> 6, ln = tid & 63;
    const int d = blockIdx.x * 4 + wv;
    const int c = blockIdx.y;
    const int s0 = ln * 4;
    const int t0 = c * TCv;

    const float4 al = *(const float4*)(A_log + d * S + s0);
    float4 A;
    A.x = -__expf(al.x); A.y = -__expf(al.y);
    A.z = -__expf(al.z); A.w = -__expf(al.w);

    float4 h = make_float4(0.f, 0.f, 0.f, 0.f);
    float cd = 0.0f;

    for (int tb = 0; tb < TCv; tb += 8) {
#pragma unroll
        for (int i = 0; i < 8; i++) {
            const int tt = t0 + tb + i;
            const float dd = delta[tt * DI + d];
            cd += dd;
            const float u = dd * xs[tt * DI + d];
            const float4 B = *(const float4*)(Bm + tt * S + s0);
            h.x = __expf(dd * A.x) * h.x + u * B.x;
            h.y = __expf(dd * A.y) * h.y + u * B.y;
            h.z = __expf(dd * A.z) * h.z + u * B.z;
            h.w = __expf(dd * A.w) * h.w + u * B.w;
        }
    }

    *(float4*)(hloc + ((size_t)(c * DI + d)) * S + s0) = h;
    if (ln == 0) Dchunk[c * DI + d] = cd;
}

template <int NCv>
__global__ __launch_bounds__(256) void k3d_down(
    const float* __restrict__ A_log, const float* __restrict__ delta,
    const float* __restrict__ xs, const float* __restrict__ Bm,
    const float* __restrict__ Cm, const float* __restrict__ hloc,
    const float* __restrict__ Dchunk, float* __restrict__ y)
{
    constexpr int TCv = BATCH / NCv;
    const int tid = threadIdx.x;
    const int wv = tid >> 6, ln = tid & 63;
    const int d = blockIdx.x * 4 + wv;
    // heaviest-carry chunks first (scheduler dispatches roughly in order)
    const int c = (NCv - 1) - blockIdx.y;
    const int s0 = ln * 4;
    const int t0 = c * TCv;

    const float4 al = *(const float4*)(A_log + d * S + s0);
    float4 A;
    A.x = -__expf(al.x); A.y = -__expf(al.y);
    A.z = -__expf(al.z); A.w = -__expf(al.w);

    // carry: h_in[c] via the serial recurrence h = hloc[cp-1] + exp(A*D[cp-1])*h
    float4 h = make_float4(0.f, 0.f, 0.f, 0.f);
    for (int cp = 1; cp <= c; cp++) {
        const float4 hl = *(const float4*)(hloc + ((size_t)((cp - 1) * DI + d)) * S + s0);
        const float Dc = Dchunk[(cp - 1) * DI + d];
        h.x = hl.x + __expf(A.x * Dc) * h.x;
        h.y = hl.y + __expf(A.y * Dc) * h.y;
        h.z = hl.z + __expf(A.z * Dc) * h.z;
        h.w = hl.w + __expf(A.w * Dc) * h.w;
    }

    float pr[8];
    for (int tb = 0; tb < TCv; tb += 8) {
#pragma unroll
        for (int i = 0; i < 8; i++) {
            const int tt = t0 + tb + i;
            const float dd = delta[tt * DI + d];
            const float u = dd * xs[tt * DI + d];
            const float4 B = *(const float4*)(Bm + tt * S + s0);
            const float4 C = *(const float4*)(Cm + tt * S + s0);
            h.x = __expf(dd * A.x) * h.x + u * B.x;
            h.y = __expf(dd * A.y) * h.y + u * B.y;
            h.z = __expf(dd * A.z) * h.z + u * B.z;
            h.w = __expf(dd * A.w) * h.w + u * B.w;
            pr[i] = h.x * C.x + h.y * C.y + h.z * C.z + h.w * C.w;
        }
#pragma unroll
        for (int i = 0; i < 8; i++) {
#pragma unroll
            for (int m = 1; m < 64; m <<= 1) pr[i] += __shfl_xor(pr[i], m, 64);
        }
        if (ln == 0) {
#pragma unroll
            for (int i = 0; i < 8; i++) y[(t0 + tb + i) * DI + d] = pr[i];
        }
    }
}

// ---------------------------------------------------------------------------
// K4: yf = (y + xs*Dp)*silu(zg); feat = yf @ W_outT; 3 head matmuls -> d_out
// ---------------------------------------------------------------------------
__global__ __launch_bounds__(256) void k4_heads(
    const float* __restrict__ y, const float* __restrict__ xs,
    const float* __restrict__ Dp, const float* __restrict__ zg,
    const float* __restrict__ W_outT,
    const float* __restrict__ We, const float* __restrict__ be,
    const float* __restrict__ Wa, const float* __restrict__ ba,
    const float* __restrict__ Wq, const float* __restrict__ bq,
    float* __restrict__ out)
{
    const int bb = blockIdx.x * 2;
    const int tid = threadIdx.x;
    __shared__ float yf[2][DI];
    __shared__ float feat[2][E];

    for (int idx = tid; idx < 2 * DI; idx += 256) {
        const int r = idx >> 8, c = idx & 255;
        const int b = bb + r;
        const float z = zg[b * DI + c];
        yf[r][c] = (y[b * DI + c] + xs[b * DI + c] * Dp[c]) * silu_f(z);
    }
    __syncthreads();

    {
        const int r = tid >> 7, e = tid & 127;
        float a = 0.0f;
#pragma unroll 8
        for (int dd = 0; dd < DI; dd++) a += yf[r][dd] * W_outT[dd * E + e];
        feat[r][e] = a;
    }
    __syncthreads();

    if (tid < 16) {
        const int r = tid >> 3, hd = tid & 7;
        const int b = bb + r;
        const float* wrow;
        float bias;
        int dst;
        if (hd == 0)      { wrow = We;                 bias = be[0];      dst = b; }
        else if (hd < 4)  { wrow = Wa + (hd - 1) * E;  bias = ba[hd - 1]; dst = 512 + b * 3 + (hd - 1); }
        else              { wrow = Wq + (hd - 4) * E;  bias = bq[hd - 4]; dst = 2048 + b * 4 + (hd - 4); }
        float a = bias;
#pragma unroll 4
        for (int e = 0; e < E; e++) a += feat[r][e] * wrow[e];
        out[dst] = a;
    }
}

// ---------------------------------------------------------------------------
template <int NCv>
static void launch_scan(const float* A_log, const float* delta, const float* xs,
                        const float* Bm, const float* Cm, float* y,
                        float* hloc, float* Dchunk, hipStream_t stream)
{
    k3u_up<NCv><<<dim3(64, NCv), 256, 0, stream>>>(A_log, delta, xs, Bm, hloc, Dchunk);
    k3d_down<NCv><<<dim3(64, NCv), 256, 0, stream>>>(A_log, delta, xs, Bm, Cm, hloc, Dchunk, y);
}

extern "C" void kernel_launch(void* const* d_in, const int* in_sizes, int n_in,
                              void* d_out, int out_size, void* d_ws, size_t ws_size,
                              hipStream_t stream)
{
    const float* x        = (const float*)d_in[0];
    const float* conv_w   = (const float*)d_in[1];
    const float* conv_b   = (const float*)d_in[2];
    const float* lin_w    = (const float*)d_in[3];
    const float* lin_b    = (const float*)d_in[4];
    const float* W_in     = (const float*)d_in[5];
    const float* conv1d_w = (const float*)d_in[6];
    const float* conv1d_b = (const float*)d_in[7];
    const float* W_x      = (const float*)d_in[8];
    const float* W_dt     = (const float*)d_in[9];
    const float* b_dt     = (const float*)d_in[10];
    const float* A_log    = (const float*)d_in[11];
    const float* Dp       = (const float*)d_in[12];
    const float* W_out    = (const float*)d_in[13];
    const float* We       = (const float*)d_in[14];
    const float* be       = (const float*)d_in[15];
    const float* Wa       = (const float*)d_in[16];
    const float* ba       = (const float*)d_in[17];
    const float* Wq       = (const float*)d_in[18];
    const float* bq       = (const float*)d_in[19];
    float* out = (float*)d_out;

    float* ws = (float*)d_ws;
    float* xm     = ws;                    // 512*256 each below
    float* zg     = xm     + 512 * 256;
    float* xs     = zg     + 512 * 256;
    float* delta  = xs     + 512 * 256;
    float* Bm     = delta  + 512 * 256;
    float* Cm     = Bm     + 512 * 256;
    float* y      = Cm     + 512 * 256;
    float* W_xT   = y      + 512 * 256;    // 256*520
    float* W_outT = W_xT   + 256 * JWX;    // 256*128
    float* tail   = W_outT + 256 * 128;    // hloc / Dchunk

    const size_t base_floats = (size_t)(tail - ws);
    const size_t avail = ws_size / 4 - base_floats;

    kA_pre<<<523, 256, 0, stream>>>(x, conv_w, conv_b, lin_w, lin_b,
                                    W_in, W_x, W_out,
                                    xm, zg, W_xT, W_outT);
    k2b_conv_wx<<<dim3(128, 9), 256, 0, stream>>>(xm, conv1d_w, conv1d_b, W_xT, W_dt, b_dt,
                                                  xs, delta, Bm, Cm);

    // need: NC*DI*S + NC*DI floats for hloc + Dchunk
    if (avail >= (size_t)32 * DI * S + 32 * DI) {
        float* hloc = tail;
        float* Dch  = hloc + (size_t)32 * DI * S;
        launch_scan<32>(A_log, delta, xs, Bm, Cm, y, hloc, Dch, stream);
    } else if (avail >= (size_t)16 * DI * S + 16 * DI) {
        float* hloc = tail;
        float* Dch  = hloc + (size_t)16 * DI * S;
        launch_scan<16>(A_log, delta, xs, Bm, Cm, y, hloc, Dch, stream);
    } else {
        float* hloc = tail;
        float* Dch  = hloc + (size_t)8 * DI * S;
        launch_scan<8>(A_log, delta, xs, Bm, Cm, y, hloc, Dch, stream);
    }

    k4_heads<<<256, 256, 0, stream>>>(y, xs, Dp, zg, W_outT, We, be, Wa, ba, Wq, bq, out);
}